// Round 2
// baseline (529.144 us; speedup 1.0000x reference)
//
#include <hip/hip_runtime.h>

// ---------------------------------------------------------------------------
// CA2_82300163326041: dual cross-attention fusion, MI355X bf16-MFMA pipeline.
//   k0 cvt     : X,Y fp32 -> bf16 (big path; lands in attn region, lifetimes
//                disjoint: k0 writes, k1 reads, k3 overwrites)
//   k1 q_gemm  : Qcat[16384,1024](bf16) = [X|Y] @ [W_xq|W_yq]^T + bias
//                (big path: A-side global_load_lds DMA from Xb/Yb)
//   k2 kv_gemm : Kf[16384,512](bf16), Vt[8][512][2048](bf16 transposed V_f)
//                A-side (Qcat, bf16) DMA-staged; W fp32 reg-staged.
//   k3 attn    : flash-style, WG = 64 q-rows x 4 waves, ONE barrier/iter,
//                QK(kb) + PV(kb-1) pipelined. V loads issued BEFORE K-DMA so
//                PV waits vmcnt(8), not vmcnt(0) (K-DMA stays in flight to
//                the barrier). Pl stride 36 (18 banks) kills 4-way write
//                conflicts; setprio(1) around the MFMA clusters.
//   k4 add     : out = X + Y + attn0 + attn1   (fp32)
// MFMA layouts (measured, guide §3): A[m=lane&15][k=quad*8+j],
// Bt[n=lane&15][k=quad*8+j], D: col=lane&15, row=quad*4+reg.
// Occupancy: register-capped at 2 waves/SIMD (acc 128 + Q 64 + V 32); LDS
// 75 KiB also caps 2 blocks/CU — consistent, don't fight it this round.
// ---------------------------------------------------------------------------

#define B_    8
#define S_    2048
#define D_    512
#define M_TOT (B_ * S_) /* 16384 */

typedef __bf16 bf16_t;
typedef __bf16 bf16x8 __attribute__((ext_vector_type(8)));
typedef __bf16 bf16x4 __attribute__((ext_vector_type(4)));
typedef float  f32x4  __attribute__((ext_vector_type(4)));

typedef __attribute__((address_space(1))) const void* gas_cv;
typedef __attribute__((address_space(3))) void*       las_v;

__device__ __forceinline__ f32x4 mfma16(bf16x8 a, bf16x8 b, f32x4 c) {
    return __builtin_amdgcn_mfma_f32_16x16x32_bf16(a, b, c, 0, 0, 0);
}
__device__ __forceinline__ void load_lds16(const void* g, void* l) {
    __builtin_amdgcn_global_load_lds((gas_cv)g, (las_v)l, 16, 0, 0);
}

// ---------------------------------------------------------------------------
// k0: X,Y fp32 -> bf16 (enables DMA staging in k1)
// ---------------------------------------------------------------------------
__global__ __launch_bounds__(256) void k_cvt(
    const float* __restrict__ X, const float* __restrict__ Y,
    bf16_t* __restrict__ Xb, bf16_t* __restrict__ Yb)
{
    const int n4 = M_TOT * 512 / 4;
    for (int i = blockIdx.x * 256 + threadIdx.x; i < n4; i += 2048 * 256) {
        const float4 x = *(const float4*)(X + (size_t)i * 4);
        bf16x4 px = { (bf16_t)x.x, (bf16_t)x.y, (bf16_t)x.z, (bf16_t)x.w };
        *(bf16x4*)(Xb + (size_t)i * 4) = px;
        const float4 y = *(const float4*)(Y + (size_t)i * 4);
        bf16x4 py = { (bf16_t)y.x, (bf16_t)y.y, (bf16_t)y.z, (bf16_t)y.w };
        *(bf16x4*)(Yb + (size_t)i * 4) = py;
    }
}

// ---------------------------------------------------------------------------
// k1 (small-ws fallback): fp32 A reg-staged, as verified baseline.
// ---------------------------------------------------------------------------
__global__ __launch_bounds__(256) void k_qgemm(
    const float* __restrict__ X, const float* __restrict__ Y,
    const float* __restrict__ Wxq, const float* __restrict__ bxq,
    const float* __restrict__ Wyq, const float* __restrict__ byq,
    bf16_t* __restrict__ Qcat)
{
    __shared__ __attribute__((aligned(16))) bf16_t Al[128 * 40];
    __shared__ __attribute__((aligned(16))) bf16_t Bl[128 * 40];
    const int m0 = blockIdx.x * 128;
    const int n0 = blockIdx.y * 128;
    const bool second = (n0 >= 512);
    const float* A    = second ? Y : X;
    const float* W    = second ? Wyq : Wxq;
    const float* bias = second ? byq : bxq;
    const int nw = n0 & 511;
    const int t    = threadIdx.x;
    const int lane = t & 63;
    const int wv   = t >> 6;
    const int wm   = (wv & 1) * 64;
    const int wn   = (wv >> 1) * 64;
    const int l15  = lane & 15;
    const int quad = lane >> 4;

    f32x4 acc[4][4] = {};

    for (int k0 = 0; k0 < 512; k0 += 32) {
        __syncthreads();
#pragma unroll
        for (int p = 0; p < 4; ++p) {
            const int lin = p * 256 + t;
            const int row = lin >> 3;
            const int ch  = (lin & 7) * 4;
            const float4 va = *(const float4*)(A + (size_t)(m0 + row) * 512 + k0 + ch);
            bf16x4 pa = { (bf16_t)va.x, (bf16_t)va.y, (bf16_t)va.z, (bf16_t)va.w };
            *(bf16x4*)(Al + row * 40 + ch) = pa;
            const float4 vb = *(const float4*)(W + (size_t)(nw + row) * 512 + k0 + ch);
            bf16x4 pb = { (bf16_t)vb.x, (bf16_t)vb.y, (bf16_t)vb.z, (bf16_t)vb.w };
            *(bf16x4*)(Bl + row * 40 + ch) = pb;
        }
        __syncthreads();
        bf16x8 af[4], bfr[4];
#pragma unroll
        for (int i = 0; i < 4; ++i)
            af[i] = *(const bf16x8*)(Al + (wm + i * 16 + l15) * 40 + quad * 8);
#pragma unroll
        for (int i = 0; i < 4; ++i)
            bfr[i] = *(const bf16x8*)(Bl + (wn + i * 16 + l15) * 40 + quad * 8);
#pragma unroll
        for (int mt = 0; mt < 4; ++mt)
#pragma unroll
            for (int nt = 0; nt < 4; ++nt)
                acc[mt][nt] = mfma16(af[mt], bfr[nt], acc[mt][nt]);
    }

#pragma unroll
    for (int nt = 0; nt < 4; ++nt) {
        const int col  = n0 + wn + nt * 16 + l15;
        const float bv = bias[col & 511];
#pragma unroll
        for (int mt = 0; mt < 4; ++mt) {
            const int rowb = m0 + wm + mt * 16 + quad * 4;
#pragma unroll
            for (int r = 0; r < 4; ++r)
                Qcat[(size_t)(rowb + r) * 1024 + col] = (bf16_t)(acc[mt][nt][r] + bv);
        }
    }
}

// ---------------------------------------------------------------------------
// k1 (big path): A-side DMA from pre-converted bf16, linear [128][32] LDS.
// ---------------------------------------------------------------------------
__global__ __launch_bounds__(256) void k_qgemm_dma(
    const bf16_t* __restrict__ Xb, const bf16_t* __restrict__ Yb,
    const float* __restrict__ Wxq, const float* __restrict__ bxq,
    const float* __restrict__ Wyq, const float* __restrict__ byq,
    bf16_t* __restrict__ Qcat)
{
    __shared__ __attribute__((aligned(16))) bf16_t Al[128 * 32];
    __shared__ __attribute__((aligned(16))) bf16_t Bl[128 * 32];
    const int m0 = blockIdx.x * 128;
    const int n0 = blockIdx.y * 128;
    const bool second = (n0 >= 512);
    const bf16_t* A   = second ? Yb : Xb;
    const float* W    = second ? Wyq : Wxq;
    const float* bias = second ? byq : bxq;
    const int nw = n0 & 511;
    const int t    = threadIdx.x;
    const int lane = t & 63;
    const int wv   = t >> 6;
    const int wm   = (wv & 1) * 64;
    const int wn   = (wv >> 1) * 64;
    const int l15  = lane & 15;
    const int quad = lane >> 4;

    // DMA source indexing: lin*8 elems -> row=lin>>2, col=(lin&3)*8 (16B/lane,
    // LDS dest lane-linear as global_load_lds requires)
    const int ar0 = t >> 2,          ac0 = (t & 3) * 8;
    const int ar1 = (256 + t) >> 2,  ac1 = ((256 + t) & 3) * 8;

    f32x4 acc[4][4] = {};

    for (int k0 = 0; k0 < 512; k0 += 32) {
        __syncthreads();
        load_lds16(A + (size_t)(m0 + ar0) * 512 + k0 + ac0, Al + t * 8);
        load_lds16(A + (size_t)(m0 + ar1) * 512 + k0 + ac1, Al + (256 + t) * 8);
#pragma unroll
        for (int p = 0; p < 4; ++p) {
            const int lin = p * 256 + t;
            const int row = lin >> 3;
            const int ch  = (lin & 7) * 4;
            const float4 vb = *(const float4*)(W + (size_t)(nw + row) * 512 + k0 + ch);
            bf16x4 pb = { (bf16_t)vb.x, (bf16_t)vb.y, (bf16_t)vb.z, (bf16_t)vb.w };
            *(bf16x4*)(Bl + row * 32 + ch) = pb;
        }
        __syncthreads();
        bf16x8 af[4], bfr[4];
#pragma unroll
        for (int i = 0; i < 4; ++i)
            af[i] = *(const bf16x8*)(Al + (wm + i * 16 + l15) * 32 + quad * 8);
#pragma unroll
        for (int i = 0; i < 4; ++i)
            bfr[i] = *(const bf16x8*)(Bl + (wn + i * 16 + l15) * 32 + quad * 8);
#pragma unroll
        for (int mt = 0; mt < 4; ++mt)
#pragma unroll
            for (int nt = 0; nt < 4; ++nt)
                acc[mt][nt] = mfma16(af[mt], bfr[nt], acc[mt][nt]);
    }

#pragma unroll
    for (int nt = 0; nt < 4; ++nt) {
        const int col  = n0 + wn + nt * 16 + l15;
        const float bv = bias[col & 511];
#pragma unroll
        for (int mt = 0; mt < 4; ++mt) {
            const int rowb = m0 + wm + mt * 16 + quad * 4;
#pragma unroll
            for (int r = 0; r < 4; ++r)
                Qcat[(size_t)(rowb + r) * 1024 + col] = (bf16_t)(acc[mt][nt][r] + bv);
        }
    }
}

// ---------------------------------------------------------------------------
// k2: [Kf | Vf] = Qcat @ [W_fk | W_fv]^T + bias.  K=1024.  Kf row-major.
// A-side (bf16 Qcat) DMA-staged into linear [128][32]; W fp32 reg-staged.
// Vf stored TRANSPOSED per batch Vt[b][d][s] via LDS transpose (union).
// ---------------------------------------------------------------------------
__global__ __launch_bounds__(256) void k_kvgemm(
    const bf16_t* __restrict__ Qcat,
    const float* __restrict__ Wfk, const float* __restrict__ bfk,
    const float* __restrict__ Wfv, const float* __restrict__ bfv,
    bf16_t* __restrict__ Kf, bf16_t* __restrict__ Vt)
{
    __shared__ __attribute__((aligned(16))) union {
        struct { bf16_t Al[128 * 32]; bf16_t Bl[128 * 32]; } g;
        bf16_t T[128 * 132];   // [d_local][s_local], pad 128->132
    } sm;
    const int m0 = blockIdx.x * 128;
    const int n0 = blockIdx.y * 128;
    const bool isV = (n0 >= 512);
    const float* W    = isV ? Wfv : Wfk;
    const float* bias = isV ? bfv : bfk;
    const int nw = n0 & 511;
    const int t    = threadIdx.x;
    const int lane = t & 63;
    const int wv   = t >> 6;
    const int wm   = (wv & 1) * 64;
    const int wn   = (wv >> 1) * 64;
    const int l15  = lane & 15;
    const int quad = lane >> 4;

    const int ar0 = t >> 2,          ac0 = (t & 3) * 8;
    const int ar1 = (256 + t) >> 2,  ac1 = ((256 + t) & 3) * 8;

    f32x4 acc[4][4] = {};

    for (int k0 = 0; k0 < 1024; k0 += 32) {
        __syncthreads();
        load_lds16(Qcat + (size_t)(m0 + ar0) * 1024 + k0 + ac0, sm.g.Al + t * 8);
        load_lds16(Qcat + (size_t)(m0 + ar1) * 1024 + k0 + ac1, sm.g.Al + (256 + t) * 8);
#pragma unroll
        for (int p = 0; p < 4; ++p) {
            const int lin = p * 256 + t;
            const int row = lin >> 3;
            const int ch  = (lin & 7) * 4;
            const float4 vb = *(const float4*)(W + (size_t)(nw + row) * 1024 + k0 + ch);
            bf16x4 pb = { (bf16_t)vb.x, (bf16_t)vb.y, (bf16_t)vb.z, (bf16_t)vb.w };
            *(bf16x4*)(sm.g.Bl + row * 32 + ch) = pb;
        }
        __syncthreads();
        bf16x8 af[4], bfr[4];
#pragma unroll
        for (int i = 0; i < 4; ++i)
            af[i] = *(const bf16x8*)(sm.g.Al + (wm + i * 16 + l15) * 32 + quad * 8);
#pragma unroll
        for (int i = 0; i < 4; ++i)
            bfr[i] = *(const bf16x8*)(sm.g.Bl + (wn + i * 16 + l15) * 32 + quad * 8);
#pragma unroll
        for (int mt = 0; mt < 4; ++mt)
#pragma unroll
            for (int nt = 0; nt < 4; ++nt)
                acc[mt][nt] = mfma16(af[mt], bfr[nt], acc[mt][nt]);
    }

    if (!isV) {
#pragma unroll
        for (int nt = 0; nt < 4; ++nt) {
            const int col  = n0 + wn + nt * 16 + l15;   // < 512
            const float bv = bias[col];
#pragma unroll
            for (int mt = 0; mt < 4; ++mt) {
                const int rowb = m0 + wm + mt * 16 + quad * 4;
#pragma unroll
                for (int r = 0; r < 4; ++r)
                    Kf[(size_t)(rowb + r) * 512 + col] = (bf16_t)(acc[mt][nt][r] + bv);
            }
        }
    } else {
        __syncthreads();   // staging reads of the last k-block are done
#pragma unroll
        for (int nt = 0; nt < 4; ++nt) {
            const int dl = wn + nt * 16 + l15;
            const float bv = bias[nw + dl];
#pragma unroll
            for (int mt = 0; mt < 4; ++mt) {
                const int sl = wm + mt * 16 + quad * 4;
#pragma unroll
                for (int r = 0; r < 4; ++r)
                    sm.T[dl * 132 + sl + r] = (bf16_t)(acc[mt][nt][r] + bv);
            }
        }
        __syncthreads();
        const int bb = m0 >> 11;             // batch
        const int sb = m0 & 2047;
        const int half = lane >> 5;
        const int sl4  = (lane & 31) * 4;
#pragma unroll
        for (int i = 0; i < 16; ++i) {
            const int dl = wv * 32 + i * 2 + half;
            const bf16x4 v = *(const bf16x4*)(sm.T + dl * 132 + sl4);
            *(bf16x4*)(Vt + (size_t)(bb * 512 + nw + dl) * 2048 + sb + sl4) = v;
        }
    }
}

// ---------------------------------------------------------------------------
// k3: attention. Changes this round:
//  - V loads issued BEFORE the K-DMA: vmcnt retires oldest-first, so PV's V
//    wait is vmcnt(8) and the next-tile DMA stays in flight to the barrier.
//  - Pl row stride 40 -> 36 elems (72B = 18 banks, gcd(18,32)=2): the exp
//    scalar stores drop from 4-way to 2-way (free) bank aliasing. P-fragment
//    reads become ds_read_b64 pairs (72B rows are 8B-aligned only).
//  - s_setprio(1) around the QK+PV MFMA clusters (T5).
// ---------------------------------------------------------------------------
__global__ __launch_bounds__(256, 2) void k_attn(
    const bf16_t* __restrict__ Qcat, const bf16_t* __restrict__ Kf,
    const bf16_t* __restrict__ Vt,
    const float* __restrict__ X, const float* __restrict__ Y,
    float* __restrict__ out, bf16_t* __restrict__ attn,
    const int mode, const int which)
{
    __shared__ __attribute__((aligned(16))) bf16_t Kl[2][32 * 520];
    __shared__ __attribute__((aligned(16))) bf16_t Pl[2][64 * 36];
    __shared__ float lsumL[64];

    const int b = blockIdx.y;
    const int w = (mode == 0) ? (int)blockIdx.z : which;
    const int t    = threadIdx.x;
    const int lane = t & 63;
    const int wv   = t >> 6;
    const int l15  = lane & 15;
    const int quad = lane >> 4;
    const int q0   = blockIdx.x * 64;
    const int qw   = q0 + wv * 16;

    const bf16_t* Kbase = Kf + (size_t)b * S_ * 512;
    const bf16_t* Vbase = Vt + ((size_t)b * 512 + wv * 128) * S_;

    bf16x8 aq[16];
    {
        const bf16_t* qp = Qcat + (size_t)(b * S_ + qw + l15) * 1024 + w * 512 + quad * 8;
#pragma unroll
        for (int ks = 0; ks < 16; ++ks) aq[ks] = *(const bf16x8*)(qp + ks * 32);
    }

    f32x4 acc[4][8] = {};
    float lacc[4] = { 0.f, 0.f, 0.f, 0.f };
    const float sc2 = 0.04419417382415922f * 1.4426950408889634f;

    // ---- prologue: K0 -> Kl[0]
#pragma unroll
    for (int p = 0; p < 8; ++p) {
        const int row = wv * 8 + p;
        load_lds16(Kbase + (size_t)row * 512 + lane * 8, Kl[0] + row * 520);
    }
    __syncthreads();

    // ---- peeled iter 0
    {
#pragma unroll
        for (int p = 0; p < 8; ++p) {
            const int row = wv * 8 + p;
            load_lds16(Kbase + (size_t)(32 + row) * 512 + lane * 8, Kl[1] + row * 520);
        }
        f32x4 s0a = {}, s0b = {}, s1a = {}, s1b = {};
        __builtin_amdgcn_s_setprio(1);
#pragma unroll
        for (int ks = 0; ks < 16; ks += 2) {
            const bf16x8 b0 = *(const bf16x8*)(Kl[0] + l15 * 520 + ks * 32 + quad * 8);
            const bf16x8 b1 = *(const bf16x8*)(Kl[0] + (16 + l15) * 520 + ks * 32 + quad * 8);
            const bf16x8 c0 = *(const bf16x8*)(Kl[0] + l15 * 520 + (ks + 1) * 32 + quad * 8);
            const bf16x8 c1 = *(const bf16x8*)(Kl[0] + (16 + l15) * 520 + (ks + 1) * 32 + quad * 8);
            s0a = mfma16(aq[ks], b0, s0a);
            s1a = mfma16(aq[ks], b1, s1a);
            s0b = mfma16(aq[ks + 1], c0, s0b);
            s1b = mfma16(aq[ks + 1], c1, s1b);
        }
        __builtin_amdgcn_s_setprio(0);
        const f32x4 sA = s0a + s0b, sB = s1a + s1b;
#pragma unroll
        for (int r = 0; r < 4; ++r) {
            const float p0 = exp2f(sA[r] * sc2);
            const float p1 = exp2f(sB[r] * sc2);
            lacc[r] += p0 + p1;
            Pl[0][(wv * 16 + quad * 4 + r) * 36 + l15] = (bf16_t)p0;
            Pl[0][(wv * 16 + quad * 4 + r) * 36 + 16 + l15] = (bf16_t)p1;
        }
        __syncthreads();
    }

    // ---- main loop kb = 1..63
    for (int kb = 1; kb < 64; ++kb) {
        const int cur = kb & 1;
        const int prv = cur ^ 1;

        // V fragments FIRST (oldest vmem): PV then waits vmcnt(8), leaving
        // the K-DMA below in flight until the barrier.
        bf16x8 vb[8];
#pragma unroll
        for (int i = 0; i < 8; ++i)
            vb[i] = *(const bf16x8*)(Vbase + (size_t)(i * 16 + l15) * S_ +
                                     (kb - 1) * 32 + quad * 8);

        // stage K(kb+1) into Kl[prv] (drained at this iter's barrier)
        {
            const bf16_t* src = Kbase + (size_t)(kb + 1) * 32 * 512;
#pragma unroll
            for (int p = 0; p < 8; ++p) {
                const int row = wv * 8 + p;
                load_lds16(src + (size_t)row * 512 + lane * 8, Kl[prv] + row * 520);
            }
        }

        __builtin_amdgcn_s_setprio(1);
        // QK(kb): 4 independent 8-deep chains
        f32x4 s0a = {}, s0b = {}, s1a = {}, s1b = {};
#pragma unroll
        for (int ks = 0; ks < 16; ks += 2) {
            const bf16x8 b0 = *(const bf16x8*)(Kl[cur] + l15 * 520 + ks * 32 + quad * 8);
            const bf16x8 b1 = *(const bf16x8*)(Kl[cur] + (16 + l15) * 520 + ks * 32 + quad * 8);
            const bf16x8 c0 = *(const bf16x8*)(Kl[cur] + l15 * 520 + (ks + 1) * 32 + quad * 8);
            const bf16x8 c1 = *(const bf16x8*)(Kl[cur] + (16 + l15) * 520 + (ks + 1) * 32 + quad * 8);
            s0a = mfma16(aq[ks], b0, s0a);
            s1a = mfma16(aq[ks], b1, s1a);
            s0b = mfma16(aq[ks + 1], c0, s0b);
            s1b = mfma16(aq[ks + 1], c1, s1b);
        }

        // PV(kb-1): 32 independent MFMAs
        {
            bf16x8 ap[4];
#pragma unroll
            for (int qt = 0; qt < 4; ++qt) {
                const bf16x4 lo = *(const bf16x4*)(Pl[prv] + (qt * 16 + l15) * 36 + quad * 8);
                const bf16x4 hi = *(const bf16x4*)(Pl[prv] + (qt * 16 + l15) * 36 + quad * 8 + 4);
                ap[qt] = __builtin_shufflevector(lo, hi, 0, 1, 2, 3, 4, 5, 6, 7);
            }
#pragma unroll
            for (int dt = 0; dt < 8; ++dt)
#pragma unroll
                for (int qt = 0; qt < 4; ++qt)
                    acc[qt][dt] = mfma16(ap[qt], vb[dt], acc[qt][dt]);
        }
        __builtin_amdgcn_s_setprio(0);

        // exp(kb) -> Pl[cur]
        const f32x4 sA = s0a + s0b, sB = s1a + s1b;
#pragma unroll
        for (int r = 0; r < 4; ++r) {
            const float p0 = exp2f(sA[r] * sc2);
            const float p1 = exp2f(sB[r] * sc2);
            lacc[r] += p0 + p1;
            Pl[cur][(wv * 16 + quad * 4 + r) * 36 + l15] = (bf16_t)p0;
            Pl[cur][(wv * 16 + quad * 4 + r) * 36 + 16 + l15] = (bf16_t)p1;
        }

        __syncthreads();
    }

    // ---- epilogue: PV(63) from Pl[1]
    {
        bf16x8 vb[8];
#pragma unroll
        for (int i = 0; i < 8; ++i)
            vb[i] = *(const bf16x8*)(Vbase + (size_t)(i * 16 + l15) * S_ +
                                     63 * 32 + quad * 8);
        bf16x8 ap[4];
#pragma unroll
        for (int qt = 0; qt < 4; ++qt) {
            const bf16x4 lo = *(const bf16x4*)(Pl[1] + (qt * 16 + l15) * 36 + quad * 8);
            const bf16x4 hi = *(const bf16x4*)(Pl[1] + (qt * 16 + l15) * 36 + quad * 8 + 4);
            ap[qt] = __builtin_shufflevector(lo, hi, 0, 1, 2, 3, 4, 5, 6, 7);
        }
#pragma unroll
        for (int dt = 0; dt < 8; ++dt)
#pragma unroll
            for (int qt = 0; qt < 4; ++qt)
                acc[qt][dt] = mfma16(ap[qt], vb[dt], acc[qt][dt]);
    }

    // row-sum reduction and publish
    {
        float lrow[4];
#pragma unroll
        for (int r = 0; r < 4; ++r) {
            float v = lacc[r];
#pragma unroll
            for (int off = 1; off < 16; off <<= 1) v += __shfl_xor(v, off, 64);
            lrow[r] = v;
        }
        if (l15 == 0) {
#pragma unroll
            for (int r = 0; r < 4; ++r) lsumL[wv * 16 + quad * 4 + r] = lrow[r];
        }
    }
    __syncthreads();

#pragma unroll
    for (int qt = 0; qt < 4; ++qt) {
        f32x4 inv;
#pragma unroll
        for (int r = 0; r < 4; ++r) inv[r] = 1.0f / lsumL[qt * 16 + quad * 4 + r];
#pragma unroll
        for (int dt = 0; dt < 8; ++dt) {
            const int d = wv * 128 + dt * 16 + l15;
#pragma unroll
            for (int r = 0; r < 4; ++r) {
                const float v = acc[qt][dt][r] * inv[r];
                const size_t idx =
                    (size_t)(b * S_ + q0 + qt * 16 + quad * 4 + r) * 512 + d;
                if (mode == 0)      attn[(size_t)w * M_TOT * 512 + idx] = (bf16_t)v;
                else if (mode == 1) out[idx] = X[idx] + Y[idx] + v;
                else                out[idx] += v;
            }
        }
    }
}

// ---------------------------------------------------------------------------
// k4: out = X + Y + attn0 + attn1
// ---------------------------------------------------------------------------
__global__ __launch_bounds__(256) void k_add(
    const float* __restrict__ X, const float* __restrict__ Y,
    const bf16_t* __restrict__ a0, const bf16_t* __restrict__ a1,
    float* __restrict__ out)
{
    const size_t i = ((size_t)blockIdx.x * 256 + threadIdx.x) * 4;
    const float4 x = *(const float4*)(X + i);
    const float4 y = *(const float4*)(Y + i);
    const bf16x4 v0 = *(const bf16x4*)(a0 + i);
    const bf16x4 v1 = *(const bf16x4*)(a1 + i);
    float4 o;
    o.x = x.x + y.x + (float)v0[0] + (float)v1[0];
    o.y = x.y + y.y + (float)v0[1] + (float)v1[1];
    o.z = x.z + y.z + (float)v0[2] + (float)v1[2];
    o.w = x.w + y.w + (float)v0[3] + (float)v1[3];
    *(float4*)(out + i) = o;
}

extern "C" void kernel_launch(void* const* d_in, const int* in_sizes, int n_in,
                              void* d_out, int out_size, void* d_ws, size_t ws_size,
                              hipStream_t stream)
{
    const float* X   = (const float*)d_in[0];
    const float* Y   = (const float*)d_in[1];
    const float* Wxq = (const float*)d_in[2];
    const float* bxq = (const float*)d_in[3];
    const float* Wyq = (const float*)d_in[4];
    const float* byq = (const float*)d_in[5];
    const float* Wfk = (const float*)d_in[6];
    const float* bfk = (const float*)d_in[7];
    const float* Wfv = (const float*)d_in[8];
    const float* bfv = (const float*)d_in[9];
    float* out = (float*)d_out;
    char*  ws  = (char*)d_ws;

    // ws layout (bytes): Qcat 32MiB | Kf 16MiB | Vt 16MiB | attn 2x16MiB
    // Xb/Yb ALIAS the attn region (lifetimes disjoint: k0 writes, k1 reads,
    // k3 overwrites).
    bf16_t* Qcat = (bf16_t*)(ws);
    bf16_t* Kf   = (bf16_t*)(ws + (size_t)33554432);
    bf16_t* Vt   = (bf16_t*)(ws + (size_t)50331648);
    bf16_t* attn = (bf16_t*)(ws + (size_t)67108864);
    bf16_t* Xb   = (bf16_t*)(ws + (size_t)67108864);
    bf16_t* Yb   = (bf16_t*)(ws + (size_t)83886080);
    const bool big = ws_size >= (size_t)100663296;

    if (big) {
        k_cvt<<<dim3(2048), 256, 0, stream>>>(X, Y, Xb, Yb);
        k_qgemm_dma<<<dim3(128, 8), 256, 0, stream>>>(Xb, Yb, Wxq, bxq, Wyq, byq, Qcat);
    } else {
        k_qgemm<<<dim3(128, 8), 256, 0, stream>>>(X, Y, Wxq, bxq, Wyq, byq, Qcat);
    }
    k_kvgemm<<<dim3(128, 8), 256, 0, stream>>>(Qcat, Wfk, bfk, Wfv, bfv, Kf, Vt);
    if (big) {
        k_attn<<<dim3(32, 8, 2), 256, 0, stream>>>(Qcat, Kf, Vt, X, Y, out, attn, 0, 0);
        k_add<<<dim3(8192), 256, 0, stream>>>(X, Y, attn, attn + (size_t)M_TOT * 512, out);
    } else {
        k_attn<<<dim3(32, 8, 1), 256, 0, stream>>>(Qcat, Kf, Vt, X, Y, out, attn, 1, 0);
        k_attn<<<dim3(32, 8, 1), 256, 0, stream>>>(Qcat, Kf, Vt, X, Y, out, attn, 2, 1);
    }
}

// Round 3
// 470.685 us; speedup vs baseline: 1.1242x; 1.1242x over previous
//
#include <hip/hip_runtime.h>

// ---------------------------------------------------------------------------
// CA2_82300163326041: dual cross-attention fusion, MI355X bf16-MFMA pipeline.
//   k1 q_gemm  : Qcat[16384,1024](bf16) = [X|Y] @ [W_xq|W_yq]^T + bias
//   k2 kv_gemm : Kf[16384,512](bf16), Vt[8][512][2048](bf16 transposed V_f)
//                A-side (Qcat, bf16) DMA-staged; W fp32 reg-staged.
//   k3 attn    : flash-style, WG = 64 q-rows x 4 waves, ONE barrier/iter,
//                QK(kb)+PV(kb-1) pipelined (round-1 proven body).
//                NEW: 1-D grid + XCD swizzle — wgid%8 = batch, so all 64
//                blocks sharing one batch's K/V (4 MB) land on ONE XCD's
//                4 MB L2 (64 blocks = 32 CU x 2 blocks: exact residency).
//   k4 add     : out = X + Y + attn0 + attn1   (fp32)
// MFMA layouts (measured, guide §3): A[m=lane&15][k=quad*8+j],
// Bt[n=lane&15][k=quad*8+j], D: col=lane&15, row=quad*4+reg.
// Round-2 post-mortem: setprio + V-first + Pl-36 DOUBLED attn HBM fetch
// (cohort desync -> L2 thrash). All three reverted; locality is now enforced
// structurally by the swizzle instead.
// ---------------------------------------------------------------------------

#define B_    8
#define S_    2048
#define D_    512
#define M_TOT (B_ * S_) /* 16384 */

typedef __bf16 bf16_t;
typedef __bf16 bf16x8 __attribute__((ext_vector_type(8)));
typedef __bf16 bf16x4 __attribute__((ext_vector_type(4)));
typedef float  f32x4  __attribute__((ext_vector_type(4)));

typedef __attribute__((address_space(1))) const void* gas_cv;
typedef __attribute__((address_space(3))) void*       las_v;

__device__ __forceinline__ f32x4 mfma16(bf16x8 a, bf16x8 b, f32x4 c) {
    return __builtin_amdgcn_mfma_f32_16x16x32_bf16(a, b, c, 0, 0, 0);
}
__device__ __forceinline__ void load_lds16(const void* g, void* l) {
    __builtin_amdgcn_global_load_lds((gas_cv)g, (las_v)l, 16, 0, 0);
}

// ---------------------------------------------------------------------------
// k1: Qcat = [X|Y] @ [W_xq|W_yq]^T + bias. 128x128 tile, BK=32, fp32->bf16
// conversion during LDS staging. (round-1 proven version)
// ---------------------------------------------------------------------------
__global__ __launch_bounds__(256) void k_qgemm(
    const float* __restrict__ X, const float* __restrict__ Y,
    const float* __restrict__ Wxq, const float* __restrict__ bxq,
    const float* __restrict__ Wyq, const float* __restrict__ byq,
    bf16_t* __restrict__ Qcat)
{
    __shared__ __attribute__((aligned(16))) bf16_t Al[128 * 40];
    __shared__ __attribute__((aligned(16))) bf16_t Bl[128 * 40];
    const int m0 = blockIdx.x * 128;
    const int n0 = blockIdx.y * 128;
    const bool second = (n0 >= 512);
    const float* A    = second ? Y : X;
    const float* W    = second ? Wyq : Wxq;
    const float* bias = second ? byq : bxq;
    const int nw = n0 & 511;
    const int t    = threadIdx.x;
    const int lane = t & 63;
    const int wv   = t >> 6;
    const int wm   = (wv & 1) * 64;
    const int wn   = (wv >> 1) * 64;
    const int l15  = lane & 15;
    const int quad = lane >> 4;

    f32x4 acc[4][4] = {};

    for (int k0 = 0; k0 < 512; k0 += 32) {
        __syncthreads();
#pragma unroll
        for (int p = 0; p < 4; ++p) {
            const int lin = p * 256 + t;
            const int row = lin >> 3;
            const int ch  = (lin & 7) * 4;
            const float4 va = *(const float4*)(A + (size_t)(m0 + row) * 512 + k0 + ch);
            bf16x4 pa = { (bf16_t)va.x, (bf16_t)va.y, (bf16_t)va.z, (bf16_t)va.w };
            *(bf16x4*)(Al + row * 40 + ch) = pa;
            const float4 vb = *(const float4*)(W + (size_t)(nw + row) * 512 + k0 + ch);
            bf16x4 pb = { (bf16_t)vb.x, (bf16_t)vb.y, (bf16_t)vb.z, (bf16_t)vb.w };
            *(bf16x4*)(Bl + row * 40 + ch) = pb;
        }
        __syncthreads();
        bf16x8 af[4], bfr[4];
#pragma unroll
        for (int i = 0; i < 4; ++i)
            af[i] = *(const bf16x8*)(Al + (wm + i * 16 + l15) * 40 + quad * 8);
#pragma unroll
        for (int i = 0; i < 4; ++i)
            bfr[i] = *(const bf16x8*)(Bl + (wn + i * 16 + l15) * 40 + quad * 8);
#pragma unroll
        for (int mt = 0; mt < 4; ++mt)
#pragma unroll
            for (int nt = 0; nt < 4; ++nt)
                acc[mt][nt] = mfma16(af[mt], bfr[nt], acc[mt][nt]);
    }

#pragma unroll
    for (int nt = 0; nt < 4; ++nt) {
        const int col  = n0 + wn + nt * 16 + l15;
        const float bv = bias[col & 511];
#pragma unroll
        for (int mt = 0; mt < 4; ++mt) {
            const int rowb = m0 + wm + mt * 16 + quad * 4;
#pragma unroll
            for (int r = 0; r < 4; ++r)
                Qcat[(size_t)(rowb + r) * 1024 + col] = (bf16_t)(acc[mt][nt][r] + bv);
        }
    }
}

// ---------------------------------------------------------------------------
// k2: [Kf | Vf] = Qcat @ [W_fk | W_fv]^T + bias.  K=1024.  Kf row-major.
// A-side (bf16 Qcat) DMA-staged into linear [128][32]; W fp32 reg-staged.
// Vf stored TRANSPOSED per batch Vt[b][d][s] via LDS transpose (union).
// ---------------------------------------------------------------------------
__global__ __launch_bounds__(256) void k_kvgemm(
    const bf16_t* __restrict__ Qcat,
    const float* __restrict__ Wfk, const float* __restrict__ bfk,
    const float* __restrict__ Wfv, const float* __restrict__ bfv,
    bf16_t* __restrict__ Kf, bf16_t* __restrict__ Vt)
{
    __shared__ __attribute__((aligned(16))) union {
        struct { bf16_t Al[128 * 32]; bf16_t Bl[128 * 32]; } g;
        bf16_t T[128 * 132];   // [d_local][s_local], pad 128->132
    } sm;
    const int m0 = blockIdx.x * 128;
    const int n0 = blockIdx.y * 128;
    const bool isV = (n0 >= 512);
    const float* W    = isV ? Wfv : Wfk;
    const float* bias = isV ? bfv : bfk;
    const int nw = n0 & 511;
    const int t    = threadIdx.x;
    const int lane = t & 63;
    const int wv   = t >> 6;
    const int wm   = (wv & 1) * 64;
    const int wn   = (wv >> 1) * 64;
    const int l15  = lane & 15;
    const int quad = lane >> 4;

    const int ar0 = t >> 2,          ac0 = (t & 3) * 8;
    const int ar1 = (256 + t) >> 2,  ac1 = ((256 + t) & 3) * 8;

    f32x4 acc[4][4] = {};

    for (int k0 = 0; k0 < 1024; k0 += 32) {
        __syncthreads();
        load_lds16(Qcat + (size_t)(m0 + ar0) * 1024 + k0 + ac0, sm.g.Al + t * 8);
        load_lds16(Qcat + (size_t)(m0 + ar1) * 1024 + k0 + ac1, sm.g.Al + (256 + t) * 8);
#pragma unroll
        for (int p = 0; p < 4; ++p) {
            const int lin = p * 256 + t;
            const int row = lin >> 3;
            const int ch  = (lin & 7) * 4;
            const float4 vb = *(const float4*)(W + (size_t)(nw + row) * 1024 + k0 + ch);
            bf16x4 pb = { (bf16_t)vb.x, (bf16_t)vb.y, (bf16_t)vb.z, (bf16_t)vb.w };
            *(bf16x4*)(sm.g.Bl + row * 32 + ch) = pb;
        }
        __syncthreads();
        bf16x8 af[4], bfr[4];
#pragma unroll
        for (int i = 0; i < 4; ++i)
            af[i] = *(const bf16x8*)(sm.g.Al + (wm + i * 16 + l15) * 32 + quad * 8);
#pragma unroll
        for (int i = 0; i < 4; ++i)
            bfr[i] = *(const bf16x8*)(sm.g.Bl + (wn + i * 16 + l15) * 32 + quad * 8);
#pragma unroll
        for (int mt = 0; mt < 4; ++mt)
#pragma unroll
            for (int nt = 0; nt < 4; ++nt)
                acc[mt][nt] = mfma16(af[mt], bfr[nt], acc[mt][nt]);
    }

    if (!isV) {
#pragma unroll
        for (int nt = 0; nt < 4; ++nt) {
            const int col  = n0 + wn + nt * 16 + l15;   // < 512
            const float bv = bias[col];
#pragma unroll
            for (int mt = 0; mt < 4; ++mt) {
                const int rowb = m0 + wm + mt * 16 + quad * 4;
#pragma unroll
                for (int r = 0; r < 4; ++r)
                    Kf[(size_t)(rowb + r) * 512 + col] = (bf16_t)(acc[mt][nt][r] + bv);
            }
        }
    } else {
        __syncthreads();   // staging reads of the last k-block are done
#pragma unroll
        for (int nt = 0; nt < 4; ++nt) {
            const int dl = wn + nt * 16 + l15;
            const float bv = bias[nw + dl];
#pragma unroll
            for (int mt = 0; mt < 4; ++mt) {
                const int sl = wm + mt * 16 + quad * 4;
#pragma unroll
                for (int r = 0; r < 4; ++r)
                    sm.T[dl * 132 + sl + r] = (bf16_t)(acc[mt][nt][r] + bv);
            }
        }
        __syncthreads();
        const int bb = m0 >> 11;             // batch
        const int sb = m0 & 2047;
        const int half = lane >> 5;
        const int sl4  = (lane & 31) * 4;
#pragma unroll
        for (int i = 0; i < 16; ++i) {
            const int dl = wv * 32 + i * 2 + half;
            const bf16x4 v = *(const bf16x4*)(sm.T + dl * 132 + sl4);
            *(bf16x4*)(Vt + (size_t)(bb * 512 + nw + dl) * 2048 + sb + sl4) = v;
        }
    }
}

// ---------------------------------------------------------------------------
// k3: attention (round-1 proven body) + XCD-swizzled 1-D grid:
//   wgid & 7 = batch  ->  all blocks sharing a batch's K/V land on one XCD
//   (assumes round-robin wgid->XCD; if mapping differs this is perf-neutral).
// mode 0: grid 512 (w = wgid>>8); modes 1/2: grid 256, w = which.
// ---------------------------------------------------------------------------
__global__ __launch_bounds__(256, 2) void k_attn(
    const bf16_t* __restrict__ Qcat, const bf16_t* __restrict__ Kf,
    const bf16_t* __restrict__ Vt,
    const float* __restrict__ X, const float* __restrict__ Y,
    float* __restrict__ out, bf16_t* __restrict__ attn,
    const int mode, const int which)
{
    __shared__ __attribute__((aligned(16))) bf16_t Kl[2][32 * 520];
    __shared__ __attribute__((aligned(16))) bf16_t Pl[2][64 * 40];
    __shared__ float lsumL[64];

    const int wgid = blockIdx.x;
    const int b  = wgid & 7;
    const int qx = (wgid >> 3) & 31;
    const int w  = (mode == 0) ? (wgid >> 8) : which;
    const int t    = threadIdx.x;
    const int lane = t & 63;
    const int wv   = t >> 6;
    const int l15  = lane & 15;
    const int quad = lane >> 4;
    const int q0   = qx * 64;                // WG q-tile base
    const int qw   = q0 + wv * 16;           // this wave's QK rows

    const bf16_t* Kbase = Kf + (size_t)b * S_ * 512;
    const bf16_t* Vbase = Vt + ((size_t)b * 512 + wv * 128) * S_;

    // Q fragments: A[m=l15][k=quad*8+j], rows qw..qw+15, full K=512
    bf16x8 aq[16];
    {
        const bf16_t* qp = Qcat + (size_t)(b * S_ + qw + l15) * 1024 + w * 512 + quad * 8;
#pragma unroll
        for (int ks = 0; ks < 16; ++ks) aq[ks] = *(const bf16x8*)(qp + ks * 32);
    }

    f32x4 acc[4][8] = {};   // O[q = qt*16+quad*4+r][d = wv*128+dt*16+l15]
    float lacc[4] = { 0.f, 0.f, 0.f, 0.f };   // per-lane partial row sums
    // exp2 domain: 1/sqrt(512) * log2(e)
    const float sc2 = 0.04419417382415922f * 1.4426950408889634f;

    // ---- prologue: K0 -> Kl[0]
#pragma unroll
    for (int p = 0; p < 8; ++p) {
        const int row = wv * 8 + p;
        load_lds16(Kbase + (size_t)row * 512 + lane * 8, Kl[0] + row * 520);
    }
    __syncthreads();

    // ---- peeled iter 0: DMA K1 -> Kl[1]; QK(0); exp -> Pl[0]; barrier
    {
#pragma unroll
        for (int p = 0; p < 8; ++p) {
            const int row = wv * 8 + p;
            load_lds16(Kbase + (size_t)(32 + row) * 512 + lane * 8, Kl[1] + row * 520);
        }
        f32x4 s0a = {}, s0b = {}, s1a = {}, s1b = {};
#pragma unroll
        for (int ks = 0; ks < 16; ks += 2) {
            const bf16x8 b0 = *(const bf16x8*)(Kl[0] + l15 * 520 + ks * 32 + quad * 8);
            const bf16x8 b1 = *(const bf16x8*)(Kl[0] + (16 + l15) * 520 + ks * 32 + quad * 8);
            const bf16x8 c0 = *(const bf16x8*)(Kl[0] + l15 * 520 + (ks + 1) * 32 + quad * 8);
            const bf16x8 c1 = *(const bf16x8*)(Kl[0] + (16 + l15) * 520 + (ks + 1) * 32 + quad * 8);
            s0a = mfma16(aq[ks], b0, s0a);
            s1a = mfma16(aq[ks], b1, s1a);
            s0b = mfma16(aq[ks + 1], c0, s0b);
            s1b = mfma16(aq[ks + 1], c1, s1b);
        }
        const f32x4 sA = s0a + s0b, sB = s1a + s1b;
#pragma unroll
        for (int r = 0; r < 4; ++r) {
            const float p0 = exp2f(sA[r] * sc2);
            const float p1 = exp2f(sB[r] * sc2);
            lacc[r] += p0 + p1;
            Pl[0][(wv * 16 + quad * 4 + r) * 40 + l15] = (bf16_t)p0;
            Pl[0][(wv * 16 + quad * 4 + r) * 40 + 16 + l15] = (bf16_t)p1;
        }
        __syncthreads();
    }

    // ---- main loop kb = 1..63 (branchless; kb=63's DMA prefetches junk
    //      into the dead buffer from valid ws memory — never read)
    for (int kb = 1; kb < 64; ++kb) {
        const int cur = kb & 1;
        const int prv = cur ^ 1;

        // stage K(kb+1) into Kl[prv] (drained at this iter's barrier)
        {
            const bf16_t* src = Kbase + (size_t)(kb + 1) * 32 * 512;
#pragma unroll
            for (int p = 0; p < 8; ++p) {
                const int row = wv * 8 + p;
                load_lds16(src + (size_t)row * 512 + lane * 8, Kl[prv] + row * 520);
            }
        }

        // V fragments for PV(kb-1): Bt[n=d][k=key] from Vt (L2-resident)
        bf16x8 vb[8];
#pragma unroll
        for (int i = 0; i < 8; ++i)
            vb[i] = *(const bf16x8*)(Vbase + (size_t)(i * 16 + l15) * S_ +
                                     (kb - 1) * 32 + quad * 8);

        // QK(kb): 4 independent 8-deep chains
        f32x4 s0a = {}, s0b = {}, s1a = {}, s1b = {};
#pragma unroll
        for (int ks = 0; ks < 16; ks += 2) {
            const bf16x8 b0 = *(const bf16x8*)(Kl[cur] + l15 * 520 + ks * 32 + quad * 8);
            const bf16x8 b1 = *(const bf16x8*)(Kl[cur] + (16 + l15) * 520 + ks * 32 + quad * 8);
            const bf16x8 c0 = *(const bf16x8*)(Kl[cur] + l15 * 520 + (ks + 1) * 32 + quad * 8);
            const bf16x8 c1 = *(const bf16x8*)(Kl[cur] + (16 + l15) * 520 + (ks + 1) * 32 + quad * 8);
            s0a = mfma16(aq[ks], b0, s0a);
            s1a = mfma16(aq[ks], b1, s1a);
            s0b = mfma16(aq[ks + 1], c0, s0b);
            s1b = mfma16(aq[ks + 1], c1, s1b);
        }

        // PV(kb-1): 32 independent MFMAs — fills QK dep-stalls + exp tail
        {
            bf16x8 ap[4];
#pragma unroll
            for (int qt = 0; qt < 4; ++qt)
                ap[qt] = *(const bf16x8*)(Pl[prv] + (qt * 16 + l15) * 40 + quad * 8);
#pragma unroll
            for (int dt = 0; dt < 8; ++dt)
#pragma unroll
                for (int qt = 0; qt < 4; ++qt)
                    acc[qt][dt] = mfma16(ap[qt], vb[dt], acc[qt][dt]);
        }

        // exp(kb) -> Pl[cur]
        const f32x4 sA = s0a + s0b, sB = s1a + s1b;
#pragma unroll
        for (int r = 0; r < 4; ++r) {
            const float p0 = exp2f(sA[r] * sc2);
            const float p1 = exp2f(sB[r] * sc2);
            lacc[r] += p0 + p1;
            Pl[cur][(wv * 16 + quad * 4 + r) * 40 + l15] = (bf16_t)p0;
            Pl[cur][(wv * 16 + quad * 4 + r) * 40 + 16 + l15] = (bf16_t)p1;
        }

        __syncthreads();
    }

    // ---- epilogue: PV(63) from Pl[1]
    {
        bf16x8 vb[8];
#pragma unroll
        for (int i = 0; i < 8; ++i)
            vb[i] = *(const bf16x8*)(Vbase + (size_t)(i * 16 + l15) * S_ +
                                     63 * 32 + quad * 8);
        bf16x8 ap[4];
#pragma unroll
        for (int qt = 0; qt < 4; ++qt)
            ap[qt] = *(const bf16x8*)(Pl[1] + (qt * 16 + l15) * 40 + quad * 8);
#pragma unroll
        for (int dt = 0; dt < 8; ++dt)
#pragma unroll
            for (int qt = 0; qt < 4; ++qt)
                acc[qt][dt] = mfma16(ap[qt], vb[dt], acc[qt][dt]);
    }

    // one-time row-sum reduction (16 lanes per quad) and publish
    {
        float lrow[4];
#pragma unroll
        for (int r = 0; r < 4; ++r) {
            float v = lacc[r];
#pragma unroll
            for (int off = 1; off < 16; off <<= 1) v += __shfl_xor(v, off, 64);
            lrow[r] = v;
        }
        if (l15 == 0) {
#pragma unroll
            for (int r = 0; r < 4; ++r) lsumL[wv * 16 + quad * 4 + r] = lrow[r];
        }
    }
    __syncthreads();

#pragma unroll
    for (int qt = 0; qt < 4; ++qt) {
        f32x4 inv;
#pragma unroll
        for (int r = 0; r < 4; ++r) inv[r] = 1.0f / lsumL[qt * 16 + quad * 4 + r];
#pragma unroll
        for (int dt = 0; dt < 8; ++dt) {
            const int d = wv * 128 + dt * 16 + l15;
#pragma unroll
            for (int r = 0; r < 4; ++r) {
                const float v = acc[qt][dt][r] * inv[r];
                const size_t idx =
                    (size_t)(b * S_ + q0 + qt * 16 + quad * 4 + r) * 512 + d;
                if (mode == 0)      attn[(size_t)w * M_TOT * 512 + idx] = (bf16_t)v;
                else if (mode == 1) out[idx] = X[idx] + Y[idx] + v;
                else                out[idx] += v;
            }
        }
    }
}

// ---------------------------------------------------------------------------
// k4: out = X + Y + attn0 + attn1
// ---------------------------------------------------------------------------
__global__ __launch_bounds__(256) void k_add(
    const float* __restrict__ X, const float* __restrict__ Y,
    const bf16_t* __restrict__ a0, const bf16_t* __restrict__ a1,
    float* __restrict__ out)
{
    const size_t i = ((size_t)blockIdx.x * 256 + threadIdx.x) * 4;
    const float4 x = *(const float4*)(X + i);
    const float4 y = *(const float4*)(Y + i);
    const bf16x4 v0 = *(const bf16x4*)(a0 + i);
    const bf16x4 v1 = *(const bf16x4*)(a1 + i);
    float4 o;
    o.x = x.x + y.x + (float)v0[0] + (float)v1[0];
    o.y = x.y + y.y + (float)v0[1] + (float)v1[1];
    o.z = x.z + y.z + (float)v0[2] + (float)v1[2];
    o.w = x.w + y.w + (float)v0[3] + (float)v1[3];
    *(float4*)(out + i) = o;
}

extern "C" void kernel_launch(void* const* d_in, const int* in_sizes, int n_in,
                              void* d_out, int out_size, void* d_ws, size_t ws_size,
                              hipStream_t stream)
{
    const float* X   = (const float*)d_in[0];
    const float* Y   = (const float*)d_in[1];
    const float* Wxq = (const float*)d_in[2];
    const float* bxq = (const float*)d_in[3];
    const float* Wyq = (const float*)d_in[4];
    const float* byq = (const float*)d_in[5];
    const float* Wfk = (const float*)d_in[6];
    const float* bfk = (const float*)d_in[7];
    const float* Wfv = (const float*)d_in[8];
    const float* bfv = (const float*)d_in[9];
    float* out = (float*)d_out;
    char*  ws  = (char*)d_ws;

    // ws layout (bytes): Qcat 32MiB | Kf 16MiB | Vt 16MiB | attn 2x16MiB
    bf16_t* Qcat = (bf16_t*)(ws);
    bf16_t* Kf   = (bf16_t*)(ws + (size_t)33554432);
    bf16_t* Vt   = (bf16_t*)(ws + (size_t)50331648);
    bf16_t* attn = (bf16_t*)(ws + (size_t)67108864);
    const bool big = ws_size >= (size_t)100663296;

    k_qgemm<<<dim3(128, 8), 256, 0, stream>>>(X, Y, Wxq, bxq, Wyq, byq, Qcat);
    k_kvgemm<<<dim3(128, 8), 256, 0, stream>>>(Qcat, Wfk, bfk, Wfv, bfv, Kf, Vt);
    if (big) {
        k_attn<<<dim3(512), 256, 0, stream>>>(Qcat, Kf, Vt, X, Y, out, attn, 0, 0);
        k_add<<<dim3(8192), 256, 0, stream>>>(X, Y, attn, attn + (size_t)M_TOT * 512, out);
    } else {
        k_attn<<<dim3(256), 256, 0, stream>>>(Qcat, Kf, Vt, X, Y, out, attn, 1, 0);
        k_attn<<<dim3(256), 256, 0, stream>>>(Qcat, Kf, Vt, X, Y, out, attn, 2, 1);
    }
}